// Round 10
// baseline (1265.386 us; speedup 1.0000x reference)
//
#include <hip/hip_runtime.h>

// N = 4,194,304 = NBLK * PER_BLOCK exactly.
constexpr int NBLK  = 256;    // 1 block per CU
constexpr int NTHR  = 1024;   // 16 waves: wave 0 = communicator (+1 elem/lane)
constexpr int EMAX  = 17;     // waves 1-15 carry 17 elems/lane
constexpr int PER_BLOCK = 64 + 15 * EMAX * 64;   // 16384
constexpr float DT  = 0.01f;
constexpr int DEPTH = 8;      // slot rotation depth; skew <= 2 iters -> safe

// d_ws layout (35 KB, memset 0 each launch; tag 0 / 0xAAAAAAAA never match):
//   [0, 32768)     : Slot part[DEPTH][NBLK]  tagged Sum(u_s) block partials
//   [32768, 34816) : u64  ampp[NBLK]         tagged amplitude partials
// Word: hi32 = tag (= s+1; steps+2 for amp), lo32 = f32 payload bits.
// Single writer per word; relaxed 8B agent atomics are untearable -> no RMW.
struct Slot { unsigned long long a, b; };

__device__ inline unsigned long long pack(unsigned tag, float x) {
  return ((unsigned long long)tag << 32) |
         (unsigned long long)__float_as_uint(x);
}
__device__ inline void st8(unsigned long long* p, unsigned long long v) {
  __hip_atomic_store(p, v, __ATOMIC_RELAXED, __HIP_MEMORY_SCOPE_AGENT);
}
__device__ inline unsigned long long ld8(unsigned long long* p) {
  return __hip_atomic_load(p, __ATOMIC_RELAXED, __HIP_MEMORY_SCOPE_AGENT);
}

__device__ inline void wave_sum2(float& a, float& b) {
  #pragma unroll
  for (int off = 1; off < 64; off <<= 1) {
    a += __shfl_xor(a, off);
    b += __shfl_xor(b, off);
  }
}
__device__ inline float wave_sum1(float a) {
  #pragma unroll
  for (int off = 1; off < 64; off <<= 1) a += __shfl_xor(a, off);
  return a;
}
// reduce values in lanes 0..15 (others pass 0); result valid in lane 0
__device__ inline void sum16(float& a, float& b) {
  #pragma unroll
  for (int off = 1; off < 16; off <<= 1) {
    a += __shfl_xor(a, off);
    b += __shfl_xor(b, off);
  }
}

// Poll 4 slots/lane (lane+64k) of row `sb` for `tag`; per-lane payload sums.
// Only unmatched words are re-loaded; lookahead makes round 1 succeed normally.
__device__ inline void poll4(Slot* sb, unsigned tag, int lane,
                             float& oa, float& ob) {
  unsigned long long va[4] = {0, 0, 0, 0}, vb[4] = {0, 0, 0, 0};
  while (true) {
    bool all = true;
    #pragma unroll
    for (int k = 0; k < 4; ++k) {
      if ((unsigned)(va[k] >> 32) != tag) va[k] = ld8(&sb[lane + 64 * k].a);
      if ((unsigned)(vb[k] >> 32) != tag) vb[k] = ld8(&sb[lane + 64 * k].b);
    }
    #pragma unroll
    for (int k = 0; k < 4; ++k)
      all = all && ((unsigned)(va[k] >> 32) == tag)
                && ((unsigned)(vb[k] >> 32) == tag);
    if (all) break;
    __builtin_amdgcn_s_sleep(2);   // backoff: avoid fabric-saturating hot spin
  }
  float ta = 0.f, tb = 0.f;
  #pragma unroll
  for (int k = 0; k < 4; ++k) {
    ta += __uint_as_float((unsigned)va[k]);
    tb += __uint_as_float((unsigned)vb[k]);
  }
  oa = ta; ob = tb;
}

// Algebra (2-step-lag variant of the exact mean-free transform):
//   heavy iter s:  z~_s = u_s + dtc*m_{s-2};  u_{s+1} = z~ + dt*(f_local - c*z~)
//   comm  iter s:  publish Sum(u_s) [computed end of iter s-1];
//                  poll Sum(u_{s-1}) [published a FULL STEP ago -> no hot spin];
//                  m_{s-1} = Sum(u_{s-1})/N + dtc*m_{s-2}
//   output fixup:  z_s = u_s + dtc*m_{s-1};  mean(z_s) == m_s  (self-consistent)
// Using m_{s-2} in the heavy fixup perturbs z by dtc*|m_{s-1}-m_{s-2}| ~ 1e-8
// per step (|m| ~ 1e-4 by random-phase cancellation) — far below tolerance.
// Skew between blocks <= 2 iters (iter-s entry requires completed poll of
// slot s-2), so DEPTH=8 rotation with strictly-increasing tags is ABA-safe.
__global__ __launch_bounds__(NTHR, 4)
void sl_persistent(const float* __restrict__ zr0,
                   const float* __restrict__ zi0,
                   const float* __restrict__ om_in,
                   const float* __restrict__ mu_p,
                   const float* __restrict__ cp_p,
                   const int*   __restrict__ st_p,
                   float* __restrict__ out,
                   void* __restrict__ ws,
                   int n) {
  __shared__ float2 wpart[2][16];   // per-wave partials of Sum(u_s), parity s&1
  __shared__ float  apart[16];      // per-wave amplitude partials (epilogue)
  __shared__ float2 mbuf[2];        // mbuf[s&1] = m_{s-1}, written during iter s

  Slot* part = reinterpret_cast<Slot*>(ws);
  unsigned long long* ampp =
      reinterpret_cast<unsigned long long*>((char*)ws + DEPTH * NBLK * 16);

  const int wv   = threadIdx.x >> 6;
  const int lane = threadIdx.x & 63;
  const int cnt  = (wv == 0) ? 1 : EMAX;
  const int base = blockIdx.x * PER_BLOCK;
  const int idx0 = (wv == 0) ? (base + lane)
                             : (base + 64 + (wv - 1) * (EMAX * 64) + lane);

  const float mu    = *mu_p;
  const float cpl   = *cp_p;
  const int   steps = *st_p;
  const float invN  = 1.0f / (float)n;
  const float dtc   = DT * cpl;
  const float muc   = mu - cpl;

  // ---- prologue: load u_0 = z_0; wpart[0] = partials of Sum(u_0) ----
  float ur[EMAX], ui[EMAX], om[EMAX];
  float sr = 0.f, si = 0.f;
  #pragma unroll
  for (int e = 0; e < EMAX; ++e)
    if (e < cnt) {
      const int idx = idx0 + e * 64;   // coalesced per wave
      ur[e] = zr0[idx];
      ui[e] = zi0[idx];
      om[e] = om_in[idx];
      sr += ur[e]; si += ui[e];
    }
  wave_sum2(sr, si);
  if (lane == 0 && wv < 16) wpart[0][wv] = make_float2(sr, si);
  if (threadIdx.x == 0) {
    mbuf[0] = make_float2(0.f, 0.f);   // m_{-1}
    mbuf[1] = make_float2(0.f, 0.f);   // m_{-2}
  }
  __syncthreads();

  float mregr = 0.f, mregi = 0.f;   // comm wave's running m (= m_{s-2} at iter s)

  // ---- main loop: one __syncthreads per step; comm overlaps heavy ----
  for (int s = 0; s < steps; ++s) {
    const float2 mprev = mbuf[(s + 1) & 1];   // m_{s-2}
    if (wv == 0) {
      // (1) publish slot s = Sum(u_s) over block, from parity-s wpart
      float a = 0.f, b = 0.f;
      if (lane < 16) { float2 p = wpart[s & 1][lane]; a = p.x; b = p.y; }
      sum16(a, b);
      Slot* srow = &part[(s & (DEPTH - 1)) * NBLK];
      if (lane == 0) {
        st8(&srow[blockIdx.x].a, pack((unsigned)(s + 1), a));
        st8(&srow[blockIdx.x].b, pack((unsigned)(s + 1), b));
      }
      // (2) tiny heavy share (1 elem/lane) while the store drains
      {
        const float x  = fmaf(dtc, mprev.x, ur[0]);
        const float y  = fmaf(dtc, mprev.y, ui[0]);
        const float a2 = fmaf(x, x, y * y);
        const float g  = muc - a2;
        const float dr = fmaf(g, x, -om[0] * y);
        const float di = fmaf(g, y,  om[0] * x);
        ur[0] = fmaf(DT, dr, x);
        ui[0] = fmaf(DT, di, y);
      }
      // (3) poll slot s-1 (published one FULL step ago) -> m_{s-1}
      if (s >= 1) {
        float ta, tb;
        poll4(&part[((s - 1) & (DEPTH - 1)) * NBLK], (unsigned)s, lane, ta, tb);
        wave_sum2(ta, tb);
        mregr = fmaf(dtc, mregr, ta * invN);   // m_{s-1}
        mregi = fmaf(dtc, mregi, tb * invN);
      }
      if (lane == 0) mbuf[s & 1] = make_float2(mregr, mregi);
      // (4) wave 0's partial of Sum(u_{s+1})
      float psr = ur[0], psi = ui[0];
      wave_sum2(psr, psi);
      if (lane == 0) wpart[(s + 1) & 1][0] = make_float2(psr, psi);
    } else {
      // heavy loop: 17 elems/lane, needs only m_{s-2}
      float nsr = 0.f, nsi = 0.f;
      #pragma unroll
      for (int e = 0; e < EMAX; ++e) {
        const float x  = fmaf(dtc, mprev.x, ur[e]);   // z~_s
        const float y  = fmaf(dtc, mprev.y, ui[e]);
        const float a2 = fmaf(x, x, y * y);
        const float g  = muc - a2;                    // (mu-c) - |z|^2
        const float dr = fmaf(g, x, -om[e] * y);
        const float di = fmaf(g, y,  om[e] * x);
        ur[e] = fmaf(DT, dr, x);                      // u_{s+1}
        ui[e] = fmaf(DT, di, y);
        nsr += ur[e]; nsi += ui[e];
      }
      wave_sum2(nsr, nsi);
      if (lane == 0) wpart[(s + 1) & 1][wv] = make_float2(nsr, nsi);
    }
    __syncthreads();
  }

  // ---- epilogue ----
  // comm: publish slot S (Sum u_S), poll slot S-1 -> m_{S-1} for the fixup
  if (wv == 0) {
    float a = 0.f, b = 0.f;
    if (lane < 16) { float2 p = wpart[steps & 1][lane]; a = p.x; b = p.y; }
    sum16(a, b);
    if (lane == 0) {
      Slot* sl = &part[(steps & (DEPTH - 1)) * NBLK + blockIdx.x];
      st8(&sl->a, pack((unsigned)(steps + 1), a));
      st8(&sl->b, pack((unsigned)(steps + 1), b));
    }
    float ta, tb;
    poll4(&part[((steps - 1) & (DEPTH - 1)) * NBLK], (unsigned)steps,
          lane, ta, tb);
    wave_sum2(ta, tb);
    mregr = fmaf(dtc, mregr, ta * invN);   // m_{S-1}
    mregi = fmaf(dtc, mregi, tb * invN);
    if (lane == 0) mbuf[steps & 1] = make_float2(mregr, mregi);
  }
  __syncthreads();
  const float2 mfin = mbuf[steps & 1];     // m_{S-1}

  float asum = 0.f;
  #pragma unroll
  for (int e = 0; e < EMAX; ++e)
    if (e < cnt) {
      const int idx = idx0 + e * 64;
      const float x = fmaf(dtc, mfin.x, ur[e]);   // z_final
      const float y = fmaf(dtc, mfin.y, ui[e]);
      const float amp = sqrtf(fmaf(x, x, y * y));
      out[idx]             = amp;             // amplitudes
      out[n + idx]         = atan2f(y, x);    // phases
      out[2 * n + 1 + idx] = x;               // zr
      out[3 * n + 1 + idx] = y;               // zi
      asum += amp;
    }
  asum = wave_sum1(asum);
  if (lane == 0 && wv < 16) apart[wv] = asum;
  __syncthreads();

  if (wv == 0) {
    float a = (lane < 16) ? apart[lane] : 0.f, d = 0.f;
    sum16(a, d);
    if (lane == 0)
      st8(&ampp[blockIdx.x], pack((unsigned)(steps + 2), a));
  }

  if (blockIdx.x == 0 && wv == 0) {
    // m_S = Sum(u_S)/N + dtc*m_{S-1} -> order parameter
    float ta, tb;
    poll4(&part[(steps & (DEPTH - 1)) * NBLK], (unsigned)(steps + 1),
          lane, ta, tb);
    wave_sum2(ta, tb);
    const float fmr = fmaf(dtc, mfin.x, ta * invN);
    const float fmi = fmaf(dtc, mfin.y, tb * invN);

    // mean amplitude
    unsigned long long v[4] = {0, 0, 0, 0};
    const unsigned atag = (unsigned)(steps + 2);
    while (true) {
      bool all = true;
      #pragma unroll
      for (int k = 0; k < 4; ++k) {
        if ((unsigned)(v[k] >> 32) != atag) v[k] = ld8(&ampp[lane + 64 * k]);
        all = all && ((unsigned)(v[k] >> 32) == atag);
      }
      if (all) break;
      __builtin_amdgcn_s_sleep(2);
    }
    float tot = 0.f;
    #pragma unroll
    for (int k = 0; k < 4; ++k) tot += __uint_as_float((unsigned)v[k]);
    tot = wave_sum1(tot);
    if (lane == 0) {
      out[2 * n]     = sqrtf(fmaf(fmr, fmr, fmi * fmi));  // order_parameter
      out[4 * n + 1] = tot * invN;                        // mean_amplitude
    }
  }
}

extern "C" void kernel_launch(void* const* d_in, const int* in_sizes, int n_in,
                              void* d_out, int out_size, void* d_ws, size_t ws_size,
                              hipStream_t stream) {
  const float* zr0  = (const float*)d_in[0];
  const float* zi0  = (const float*)d_in[1];
  const float* om   = (const float*)d_in[2];
  const float* mu_p = (const float*)d_in[3];
  const float* cp_p = (const float*)d_in[4];
  const int*   st_p = (const int*)d_in[5];
  float* out = (float*)d_out;
  int n = in_sizes[0];

  // zero the tag region (tag 0 never matches; 0xAA poison never matches)
  hipMemsetAsync(d_ws, 0, DEPTH * NBLK * 16 + NBLK * 8, stream);

  void* args[] = {(void*)&zr0, (void*)&zi0, (void*)&om, (void*)&mu_p,
                  (void*)&cp_p, (void*)&st_p, (void*)&out, (void*)&d_ws, (void*)&n};
  hipLaunchCooperativeKernel(reinterpret_cast<void*>(sl_persistent),
                             dim3(NBLK), dim3(NTHR), args, 0, stream);
}

// Round 11
// 217.268 us; speedup vs baseline: 5.8241x; 5.8241x over previous
//
#include <hip/hip_runtime.h>

// N = 4,194,304 = NBLK * NTHR * ELEMS exactly. Uniform layout (R7-proven).
constexpr int NBLK  = 256;    // 1 block per CU
constexpr int NTHR  = 1024;   // 16 waves, ALL carry ELEMS elems/lane (uniform)
constexpr int ELEMS = 16;
constexpr float DT  = 0.01f;
constexpr int DEPTH = 8;      // slot rotation; skew <= 2 iters -> ABA-safe

// d_ws layout (35 KB, memset 0 each launch; tag 0 / 0xAAAAAAAA never match):
//   [0, 32768)     : Slot part[DEPTH][NBLK]  tagged Sum(u_s) block sums
//   [32768, 34816) : u64  ampp[NBLK]         tagged amplitude block sums
// Word: hi32 = tag (= s+1; steps+2 for amp), lo32 = f32 payload bits.
// Single writer per word; relaxed 8B agent atomics are untearable -> no RMW.
struct Slot { unsigned long long a, b; };

__device__ inline unsigned long long pack(unsigned tag, float x) {
  return ((unsigned long long)tag << 32) |
         (unsigned long long)__float_as_uint(x);
}
__device__ inline void st8(unsigned long long* p, unsigned long long v) {
  __hip_atomic_store(p, v, __ATOMIC_RELAXED, __HIP_MEMORY_SCOPE_AGENT);
}
__device__ inline unsigned long long ld8(unsigned long long* p) {
  return __hip_atomic_load(p, __ATOMIC_RELAXED, __HIP_MEMORY_SCOPE_AGENT);
}

__device__ inline void wave_sum2(float& a, float& b) {
  #pragma unroll
  for (int off = 1; off < 64; off <<= 1) {
    a += __shfl_xor(a, off);
    b += __shfl_xor(b, off);
  }
}
__device__ inline float wave_sum1(float a) {
  #pragma unroll
  for (int off = 1; off < 64; off <<= 1) a += __shfl_xor(a, off);
  return a;
}
// reduce values in lanes 0..15 (others pass 0); lane 0 holds the result
__device__ inline void sum16(float& a, float& b) {
  #pragma unroll
  for (int off = 1; off < 16; off <<= 1) {
    a += __shfl_xor(a, off);
    b += __shfl_xor(b, off);
  }
}

// wave0-only: poll 4 slots/lane (lane+64k) of row `sb` for `tag`.
// Poll target is always >= one full iteration old (publish of slot s happens
// at iter s-1 phase B; poll of slot s at iter s phase B), so round 1 hits in
// steady state — this is the R7-proven self-paced ordering that avoids the
// R8/R9 fabric-congestion collapse (WRITE_SIZE 4 GB signature).
__device__ inline void poll4(Slot* sb, unsigned tag, int lane,
                             float& oa, float& ob) {
  unsigned long long va[4] = {0, 0, 0, 0}, vb[4] = {0, 0, 0, 0};
  while (true) {
    bool all = true;
    #pragma unroll
    for (int k = 0; k < 4; ++k) {
      if ((unsigned)(va[k] >> 32) != tag) va[k] = ld8(&sb[lane + 64 * k].a);
      if ((unsigned)(vb[k] >> 32) != tag) vb[k] = ld8(&sb[lane + 64 * k].b);
    }
    #pragma unroll
    for (int k = 0; k < 4; ++k)
      all = all && ((unsigned)(va[k] >> 32) == tag)
                && ((unsigned)(vb[k] >> 32) == tag);
    if (all) break;
    __builtin_amdgcn_s_sleep(2);
  }
  float ta = 0.f, tb = 0.f;
  #pragma unroll
  for (int k = 0; k < 4; ++k) {
    ta += __uint_as_float((unsigned)va[k]);
    tb += __uint_as_float((unsigned)vb[k]);
  }
  oa = ta; ob = tb;
}

// Exact mean-free algebra (same as R7, no lag approximation):
//   u_{s+1} = z_s + dt*(f_local(z_s) - c*z_s),  z_s = u_s + dtc*m_{s-1}
//   m_s     = Sum(u_s)/N + dtc*m_{s-1}
// Per step: A) all 16 waves heavy -> wpart; #1; B) wave0: publish Sum(u_{s+1})
// as slot s+1, poll slot s (one full iteration old), advance m -> mbuf; #2.
__global__ __launch_bounds__(NTHR, 4)
void sl_persistent(const float* __restrict__ zr0,
                   const float* __restrict__ zi0,
                   const float* __restrict__ om_in,
                   const float* __restrict__ mu_p,
                   const float* __restrict__ cp_p,
                   const int*   __restrict__ st_p,
                   float* __restrict__ out,
                   void* __restrict__ ws,
                   int n) {
  __shared__ float2 wpart[2][16];   // per-wave partials of Sum(u_s), parity s&1
  __shared__ float  apart[16];      // per-wave amplitude partials (epilogue)
  __shared__ float2 mbuf[2];        // mbuf[s&1] = m_{s-1} entering iter s

  Slot* part = reinterpret_cast<Slot*>(ws);
  unsigned long long* ampp =
      reinterpret_cast<unsigned long long*>((char*)ws + DEPTH * NBLK * 16);

  const int wv   = threadIdx.x >> 6;
  const int lane = threadIdx.x & 63;
  const int idx0 = blockIdx.x * (NTHR * ELEMS) + wv * (64 * ELEMS) + lane;

  const float mu    = *mu_p;
  const float cpl   = *cp_p;
  const int   steps = *st_p;
  const float invN  = 1.0f / (float)n;
  const float dtc   = DT * cpl;
  const float muc   = mu - cpl;

  // ---- prologue: load u_0 = z_0 (uniform, coalesced); wpart[0]; m_{-1}=0 ----
  float ur[ELEMS], ui[ELEMS], om[ELEMS];
  float sr = 0.f, si = 0.f;
  #pragma unroll
  for (int e = 0; e < ELEMS; ++e) {
    const int idx = idx0 + e * 64;
    ur[e] = zr0[idx];
    ui[e] = zi0[idx];
    om[e] = om_in[idx];
    sr += ur[e]; si += ui[e];
  }
  wave_sum2(sr, si);
  if (lane == 0) wpart[0][wv] = make_float2(sr, si);
  if (threadIdx.x == 0) mbuf[0] = make_float2(0.f, 0.f);   // m_{-1}
  __syncthreads();
  if (wv == 0) {   // publish slot 0 = Sum(u_0), tag 1
    float a = 0.f, b = 0.f;
    if (lane < 16) { float2 p = wpart[0][lane]; a = p.x; b = p.y; }
    sum16(a, b);
    if (lane == 0) {
      st8(&part[0].a + 2 * blockIdx.x, pack(1u, a));       // part[0][bid].a
      st8(&part[0].a + 2 * blockIdx.x + 1, pack(1u, b));   // part[0][bid].b
    }
  }

  float mregr = 0.f, mregi = 0.f;   // wave0's running m (= m_{s-1} after B of s-1)

  // ---- main loop: 2 barriers/step, wave0-only comm, R7-proven ordering ----
  for (int s = 0; s < steps; ++s) {
    const float2 mp = mbuf[s & 1];   // m_{s-1}
    // phase A: heavy (all 16 waves, uniform 16 elems/lane)
    float nsr = 0.f, nsi = 0.f;
    #pragma unroll
    for (int e = 0; e < ELEMS; ++e) {
      const float x  = fmaf(dtc, mp.x, ur[e]);     // z_s
      const float y  = fmaf(dtc, mp.y, ui[e]);
      const float a2 = fmaf(x, x, y * y);
      const float g  = muc - a2;                   // (mu-c) - |z|^2
      const float dr = fmaf(g, x, -om[e] * y);
      const float di = fmaf(g, y,  om[e] * x);
      ur[e] = fmaf(DT, dr, x);                     // u_{s+1}
      ui[e] = fmaf(DT, di, y);
      nsr += ur[e]; nsi += ui[e];
    }
    wave_sum2(nsr, nsi);
    if (lane == 0) wpart[(s + 1) & 1][wv] = make_float2(nsr, nsi);
    __syncthreads();   // #1: wpart complete

    if (wv == 0) {
      // publish slot s+1 = Sum(u_{s+1})
      float a = 0.f, b = 0.f;
      if (lane < 16) { float2 p = wpart[(s + 1) & 1][lane]; a = p.x; b = p.y; }
      sum16(a, b);
      Slot* srow1 = &part[((s + 1) & (DEPTH - 1)) * NBLK];
      if (lane == 0) {
        st8(&srow1[blockIdx.x].a, pack((unsigned)(s + 2), a));
        st8(&srow1[blockIdx.x].b, pack((unsigned)(s + 2), b));
      }
      // poll slot s (published at iter s-1 phase B -> full-iteration slack)
      float ta, tb;
      poll4(&part[(s & (DEPTH - 1)) * NBLK], (unsigned)(s + 1), lane, ta, tb);
      wave_sum2(ta, tb);
      mregr = fmaf(dtc, mregr, ta * invN);   // m_s
      mregi = fmaf(dtc, mregi, tb * invN);
      if (lane == 0) mbuf[(s + 1) & 1] = make_float2(mregr, mregi);
    }
    __syncthreads();   // #2: m_s visible for next iteration
  }

  // ---- epilogue: z_final = u_steps + dtc*m_{steps-1} ----
  const float2 mfin = mbuf[steps & 1];   // m_{steps-1}
  float asum = 0.f;
  #pragma unroll
  for (int e = 0; e < ELEMS; ++e) {
    const int idx = idx0 + e * 64;
    const float x = fmaf(dtc, mfin.x, ur[e]);
    const float y = fmaf(dtc, mfin.y, ui[e]);
    const float amp = sqrtf(fmaf(x, x, y * y));
    out[idx]             = amp;             // amplitudes
    out[n + idx]         = atan2f(y, x);    // phases
    out[2 * n + 1 + idx] = x;               // zr
    out[3 * n + 1 + idx] = y;               // zi
    asum += amp;
  }
  asum = wave_sum1(asum);
  if (lane == 0) apart[wv] = asum;
  __syncthreads();

  if (wv == 0) {
    float a = (lane < 16) ? apart[lane] : 0.f, d = 0.f;
    sum16(a, d);
    if (lane == 0)
      st8(&ampp[blockIdx.x], pack((unsigned)(steps + 2), a));
  }

  if (blockIdx.x == 0 && wv == 0) {
    // m_S = Sum(u_S)/N + dtc*m_{S-1}; slot S was published at iter S-1 phase B
    float ta, tb;
    poll4(&part[(steps & (DEPTH - 1)) * NBLK], (unsigned)(steps + 1),
          lane, ta, tb);
    wave_sum2(ta, tb);
    const float fmr = fmaf(dtc, mfin.x, ta * invN);
    const float fmi = fmaf(dtc, mfin.y, tb * invN);

    // mean amplitude over all blocks
    unsigned long long v[4] = {0, 0, 0, 0};
    const unsigned atag = (unsigned)(steps + 2);
    while (true) {
      bool all = true;
      #pragma unroll
      for (int k = 0; k < 4; ++k) {
        if ((unsigned)(v[k] >> 32) != atag) v[k] = ld8(&ampp[lane + 64 * k]);
        all = all && ((unsigned)(v[k] >> 32) == atag);
      }
      if (all) break;
      __builtin_amdgcn_s_sleep(2);
    }
    float tot = 0.f;
    #pragma unroll
    for (int k = 0; k < 4; ++k) tot += __uint_as_float((unsigned)v[k]);
    tot = wave_sum1(tot);
    if (lane == 0) {
      out[2 * n]     = sqrtf(fmaf(fmr, fmr, fmi * fmi));  // order_parameter
      out[4 * n + 1] = tot * invN;                        // mean_amplitude
    }
  }
}

extern "C" void kernel_launch(void* const* d_in, const int* in_sizes, int n_in,
                              void* d_out, int out_size, void* d_ws, size_t ws_size,
                              hipStream_t stream) {
  const float* zr0  = (const float*)d_in[0];
  const float* zi0  = (const float*)d_in[1];
  const float* om   = (const float*)d_in[2];
  const float* mu_p = (const float*)d_in[3];
  const float* cp_p = (const float*)d_in[4];
  const int*   st_p = (const int*)d_in[5];
  float* out = (float*)d_out;
  int n = in_sizes[0];

  // zero the tag region (tag 0 never matches; 0xAA poison never matches)
  hipMemsetAsync(d_ws, 0, DEPTH * NBLK * 16 + NBLK * 8, stream);

  void* args[] = {(void*)&zr0, (void*)&zi0, (void*)&om, (void*)&mu_p,
                  (void*)&cp_p, (void*)&st_p, (void*)&out, (void*)&d_ws, (void*)&n};
  hipLaunchCooperativeKernel(reinterpret_cast<void*>(sl_persistent),
                             dim3(NBLK), dim3(NTHR), args, 0, stream);
}